// Round 1
// baseline (483.450 us; speedup 1.0000x reference)
//
#include <hip/hip_runtime.h>

// ChannelAttentionBlock: per batch b, F = x[b] viewed as [4096,128] (row-major).
// S = F F^T ; P = softmax rows ; out[b] = F^T P  -> [128, 4096].
// Two-pass flash-style: kernel 1 computes rowmax & 1/Z; kernel 2 recomputes S
// tiles, weights, and accumulates O = F^T W via bf16 MFMA.

typedef __attribute__((ext_vector_type(8))) __bf16 bf16x8;
typedef __attribute__((ext_vector_type(4))) float f32x4;

#define MFMA(a, b, c) __builtin_amdgcn_mfma_f32_16x16x32_bf16((a), (b), (c), 0, 0, 0)

static constexpr int NT  = 4096;  // N = c*c
static constexpr int DD  = 128;   // d
static constexpr int LDF = 136;   // ushort row stride for [.. ][128] tiles (272 B: 16B-aligned, bank-spread)
static constexpr int LDT = 40;    // ushort row stride for transposed [..][32] tiles (80 B)

__device__ __forceinline__ ushort f2bf(float f) {
  union { float f; unsigned u; } v; v.f = f;
  unsigned u = v.u;
  return (ushort)((u + 0x7FFFu + ((u >> 16) & 1u)) >> 16);  // RNE
}

// ---------------------------------------------------------------------------
// Kernel 1: per-row online max & sum of exp over all m.  grid (64, B)
// ---------------------------------------------------------------------------
__global__ __launch_bounds__(256) void cab_rowstats(const float* __restrict__ x,
                                                    float2* __restrict__ stats) {
  const int b  = blockIdx.y;
  const int nb = blockIdx.x * 64;
  const float* F = x + (size_t)b * NT * DD;

  __shared__ ushort Fn[64 * LDF];
  __shared__ ushort Fm[64 * LDF];

  const int t    = threadIdx.x;
  const int lane = t & 63;
  const int wv   = t >> 6;
  const int lrow = lane & 15;
  const int lk8  = (lane >> 4) * 8;
  const int wb   = wv * 16;  // wave's n-sub-base inside the 64-row tile

  // stage Fn (this block's 64 rows), fp32 -> bf16
  for (int i = 0; i < 8; ++i) {
    int idx = t + i * 256;         // 0..2047
    int r   = idx >> 5;            // 0..63
    int sg  = idx & 31;            // float4 segment
    float4 v = *(const float4*)(F + (size_t)(nb + r) * DD + sg * 4);
    *(ushort4*)&Fn[r * LDF + sg * 4] =
        make_ushort4(f2bf(v.x), f2bf(v.y), f2bf(v.z), f2bf(v.w));
  }

  // per-lane deferred online stats for 4 rows (this lane's slice of columns)
  float mloc[4], zloc[4];
#pragma unroll
  for (int r = 0; r < 4; ++r) { mloc[r] = -3.0e38f; zloc[r] = 0.0f; }

  for (int mc = 0; mc < NT; mc += 64) {
    __syncthreads();  // previous chunk's MFMA reads of Fm done
    for (int i = 0; i < 8; ++i) {
      int idx = t + i * 256;
      int r   = idx >> 5;
      int sg  = idx & 31;
      float4 v = *(const float4*)(F + (size_t)(mc + r) * DD + sg * 4);
      *(ushort4*)&Fm[r * LDF + sg * 4] =
          make_ushort4(f2bf(v.x), f2bf(v.y), f2bf(v.z), f2bf(v.w));
    }
    __syncthreads();

    // S sub-tile: rows [nb+wb .. +15], cols [mc .. mc+63]
    f32x4 acc[4];
#pragma unroll
    for (int ct = 0; ct < 4; ++ct) acc[ct] = (f32x4){0.f, 0.f, 0.f, 0.f};
#pragma unroll
    for (int ks = 0; ks < 4; ++ks) {
      bf16x8 a = *(const bf16x8*)&Fn[(wb + lrow) * LDF + ks * 32 + lk8];
#pragma unroll
      for (int ct = 0; ct < 4; ++ct) {
        bf16x8 bb = *(const bf16x8*)&Fm[(ct * 16 + lrow) * LDF + ks * 32 + lk8];
        acc[ct] = MFMA(a, bb, acc[ct]);
      }
    }
    // D layout: row = (lane>>4)*4 + r, col = ct*16 + (lane&15)
#pragma unroll
    for (int r = 0; r < 4; ++r) {
      float s0 = acc[0][r], s1 = acc[1][r], s2 = acc[2][r], s3 = acc[3][r];
      float cmx = fmaxf(fmaxf(s0, s1), fmaxf(s2, s3));
      if (cmx > mloc[r]) {
        zloc[r] *= __expf(mloc[r] - cmx);
        mloc[r] = cmx;
      }
      zloc[r] += __expf(s0 - mloc[r]) + __expf(s1 - mloc[r]) +
                 __expf(s2 - mloc[r]) + __expf(s3 - mloc[r]);
    }
  }

  // merge across the 16 lanes sharing the same rows (vary lane&15)
#pragma unroll
  for (int r = 0; r < 4; ++r) {
    float m = mloc[r], z = zloc[r];
#pragma unroll
    for (int off = 1; off < 16; off <<= 1) {
      float mo = __shfl_xor(m, off, 64);
      float zo = __shfl_xor(z, off, 64);
      float mn = fmaxf(m, mo);
      z = z * __expf(m - mn) + zo * __expf(mo - mn);
      m = mn;
    }
    mloc[r] = m; zloc[r] = z;
  }
  if ((lane & 15) == 0) {
    int rowbase = nb + wb + (lane >> 4) * 4;
#pragma unroll
    for (int r = 0; r < 4; ++r)
      stats[(size_t)b * NT + rowbase + r] = make_float2(mloc[r], 1.0f / zloc[r]);
  }
}

// ---------------------------------------------------------------------------
// Kernel 2: O[:, mtile] = sum_n w[n,m] * F[n,:]   grid (64, B)
// ---------------------------------------------------------------------------
__global__ __launch_bounds__(256) void cab_out(const float* __restrict__ x,
                                               const float2* __restrict__ stats,
                                               float* __restrict__ out) {
  const int b   = blockIdx.y;
  const int mb0 = blockIdx.x * 64;
  const float* F = x + (size_t)b * NT * DD;
  const float2* st = stats + (size_t)b * NT;

  __shared__ ushort Fm[64 * LDF];   // m-tile rows of F (GEMM1 B)
  __shared__ ushort Fn[32 * LDF];   // n-step rows of F (GEMM1 A)
  __shared__ ushort Ft[128 * LDT];  // transposed n-step rows: Ft[d][n] (GEMM2 A)
  __shared__ ushort Wt[64 * LDT];   // Wt[m][n] (GEMM2 B)
  __shared__ float2 sst[32];

  const int t    = threadIdx.x;
  const int lane = t & 63;
  const int wv   = t >> 6;
  const int lrow = lane & 15;
  const int lk8  = (lane >> 4) * 8;
  const int mbw  = wv * 16;  // wave's m-sub-base inside the 64-col tile

  // stage Fm once
  for (int i = 0; i < 8; ++i) {
    int idx = t + i * 256;
    int r   = idx >> 5;
    int sg  = idx & 31;
    float4 v = *(const float4*)(F + (size_t)(mb0 + r) * DD + sg * 4);
    *(ushort4*)&Fm[r * LDF + sg * 4] =
        make_ushort4(f2bf(v.x), f2bf(v.y), f2bf(v.z), f2bf(v.w));
  }

  f32x4 accO[8];
#pragma unroll
  for (int dt = 0; dt < 8; ++dt) accO[dt] = (f32x4){0.f, 0.f, 0.f, 0.f};

  for (int ns = 0; ns < NT; ns += 32) {
    __syncthreads();  // previous iteration's reads of Fn/Ft/Wt done
    // stage Fn (row layout) + Ft (transposed), fp32 -> bf16
    for (int i = 0; i < 4; ++i) {
      int idx = t + i * 256;       // 0..1023
      int r   = idx >> 5;          // 0..31  (n local)
      int sg  = idx & 31;          // 0..31  (float4 segment over d)
      float4 v = *(const float4*)(F + (size_t)(ns + r) * DD + sg * 4);
      ushort w0 = f2bf(v.x), w1 = f2bf(v.y), w2 = f2bf(v.z), w3 = f2bf(v.w);
      *(ushort4*)&Fn[r * LDF + sg * 4] = make_ushort4(w0, w1, w2, w3);
      Ft[(sg * 4 + 0) * LDT + r] = w0;
      Ft[(sg * 4 + 1) * LDT + r] = w1;
      Ft[(sg * 4 + 2) * LDT + r] = w2;
      Ft[(sg * 4 + 3) * LDT + r] = w3;
    }
    if (t < 32) sst[t] = st[ns + t];
    __syncthreads();

    // GEMM1: S[32 x 16] for this wave's m-sub-tile
    f32x4 sacc[2];
    sacc[0] = (f32x4){0.f, 0.f, 0.f, 0.f};
    sacc[1] = (f32x4){0.f, 0.f, 0.f, 0.f};
#pragma unroll
    for (int ks = 0; ks < 4; ++ks) {
      bf16x8 bb = *(const bf16x8*)&Fm[(mbw + lrow) * LDF + ks * 32 + lk8];
#pragma unroll
      for (int nt = 0; nt < 2; ++nt) {
        bf16x8 a = *(const bf16x8*)&Fn[(nt * 16 + lrow) * LDF + ks * 32 + lk8];
        sacc[nt] = MFMA(a, bb, sacc[nt]);
      }
    }
    // w = exp(s - mx) * (1/Z); write Wt[m][n] as bf16
#pragma unroll
    for (int nt = 0; nt < 2; ++nt) {
      ushort4 wp;
#pragma unroll
      for (int r = 0; r < 4; ++r) {
        int nl = nt * 16 + (lane >> 4) * 4 + r;
        float2 s2 = sst[nl];
        float w = __expf(sacc[nt][r] - s2.x) * s2.y;
        ((ushort*)&wp)[r] = f2bf(w);
      }
      *(ushort4*)&Wt[(mbw + lrow) * LDT + nt * 16 + (lane >> 4) * 4] = wp;
    }
    __syncthreads();

    // GEMM2: accO[dt] += Ft(A: [d][n]) x Wt(B: [n][m]), K = 32
    {
      bf16x8 bw = *(const bf16x8*)&Wt[(mbw + lrow) * LDT + lk8];
#pragma unroll
      for (int dt = 0; dt < 8; ++dt) {
        bf16x8 a = *(const bf16x8*)&Ft[(dt * 16 + lrow) * LDT + lk8];
        accO[dt] = MFMA(a, bw, accO[dt]);
      }
    }
  }

  // epilogue: D layout row = dt*16 + (lane>>4)*4 + r (= d), col = mbw+lrow (= m)
  float* Ob = out + (size_t)b * DD * NT;
  const int m = mb0 + mbw + lrow;
#pragma unroll
  for (int dt = 0; dt < 8; ++dt) {
#pragma unroll
    for (int r = 0; r < 4; ++r) {
      int d = dt * 16 + (lane >> 4) * 4 + r;
      Ob[(size_t)d * NT + m] = accO[dt][r];
    }
  }
}

extern "C" void kernel_launch(void* const* d_in, const int* in_sizes, int n_in,
                              void* d_out, int out_size, void* d_ws, size_t ws_size,
                              hipStream_t stream) {
  const float* x = (const float*)d_in[0];
  float* out = (float*)d_out;
  float2* stats = (float2*)d_ws;  // 8*4096 float2 = 256 KB

  dim3 blk(256);
  dim3 grid(NT / 64, 8);
  hipLaunchKernelGGL(cab_rowstats, grid, blk, 0, stream, x, stats);
  hipLaunchKernelGGL(cab_out, grid, blk, 0, stream, x, stats, out);
}

// Round 3
// 304.224 us; speedup vs baseline: 1.5891x; 1.5891x over previous
//
#include <hip/hip_runtime.h>

// ChannelAttentionBlock: per batch b, F = x[b] viewed as [4096,128] (row-major).
// S = F F^T ; P = softmax rows ; out[b] = F^T P  -> [128, 4096].
//
// k0 cab_transpose: Ftb[b][d][n] = bf16(F[b][n][d])   (8 MB ws)
// k1 cab_rowstats : per-row (max, 1/Z) via flash pass  (round-1 math verbatim)
// k2 cab_out      : recompute S tiles, W = exp(S-m)/Z, O += F^T W
//
// S is computed with bit-identical bf16 operands and identical MFMA chain order
// in k1 and k2 (softmax here is razor-sharp, so this matters).
// All LDS tiles use linear rows + XOR swizzle: bytecol ^= ((row&7)<<4), applied
// on both write and read -> even bank spread for every access pattern.

typedef __attribute__((ext_vector_type(8))) __bf16 bf16x8;
typedef __attribute__((ext_vector_type(4))) __bf16 bf16x4;
typedef __attribute__((ext_vector_type(4))) float f32x4;

#define MFMA16(a, b, c) __builtin_amdgcn_mfma_f32_16x16x32_bf16((a), (b), (c), 0, 0, 0)

static constexpr int NT = 4096;
static constexpr int DD = 128;

__device__ __forceinline__ bf16x8 pack8(float4 u, float4 v) {
  bf16x8 r;
  r[0] = (__bf16)u.x; r[1] = (__bf16)u.y; r[2] = (__bf16)u.z; r[3] = (__bf16)u.w;
  r[4] = (__bf16)v.x; r[5] = (__bf16)v.y; r[6] = (__bf16)v.z; r[7] = (__bf16)v.w;
  return r;
}
__device__ __forceinline__ bf16x4 pack4(float4 u) {
  bf16x4 r;
  r[0] = (__bf16)u.x; r[1] = (__bf16)u.y; r[2] = (__bf16)u.z; r[3] = (__bf16)u.w;
  return r;
}

// ---------------------------------------------------------------------------
// Kernel 0: global transpose+cast. grid 4096: b=blk&7, seg=blk>>3: d=seg>>2,
// n0=(seg&3)*1024. Reads are 4B-scattered but L2-local per XCD (batch==XCD).
// ---------------------------------------------------------------------------
__global__ __launch_bounds__(256) void cab_transpose(const float* __restrict__ x,
                                                     ushort* __restrict__ Ftb) {
  const int blk = blockIdx.x;
  const int b = blk & 7, seg = blk >> 3;
  const int d = seg >> 2, n0 = (seg & 3) * 1024;
  const float* F = x + (size_t)b * NT * DD;
  ushort* Ob = Ftb + (size_t)b * DD * NT;
  const int n = n0 + threadIdx.x * 4;
  ushort4 w;
  w.x = __builtin_bit_cast(unsigned short, (__bf16)F[(size_t)(n + 0) * DD + d]);
  w.y = __builtin_bit_cast(unsigned short, (__bf16)F[(size_t)(n + 1) * DD + d]);
  w.z = __builtin_bit_cast(unsigned short, (__bf16)F[(size_t)(n + 2) * DD + d]);
  w.w = __builtin_bit_cast(unsigned short, (__bf16)F[(size_t)(n + 3) * DD + d]);
  *(ushort4*)(Ob + (size_t)d * NT + n) = w;
}

// ---------------------------------------------------------------------------
// Kernel 1: row stats (m, 1/Z). grid 512: b=blk&7, nb=(blk>>3)*64.
// A-fragments in registers; B from swizzled LDS tile; reg-prefetch + 2 barriers.
// ---------------------------------------------------------------------------
__global__ __launch_bounds__(256, 3) void cab_rowstats(const float* __restrict__ x,
                                                       float2* __restrict__ stats) {
  const int b = blockIdx.x & 7;
  const int nb = (blockIdx.x >> 3) * 64;
  const float* F = x + (size_t)b * NT * DD;

  const int t = threadIdx.x, lane = t & 63, wv = t >> 6;
  const int lrow = lane & 15, hi = lane >> 4, wb = wv * 16;
  const int r5 = t >> 5, sg = t & 31;
  const int swl = (lrow & 7) << 4;

  __shared__ __align__(16) char Fm[64 * 256];  // [row 0..63][256B], 16B blocks swizzled

  // own-row A fragments (bit-identical to LDS-staged values)
  bf16x8 afr[4];
#pragma unroll
  for (int ks = 0; ks < 4; ++ks) {
    const float* p = F + (size_t)(nb + wb + lrow) * DD + ks * 32 + hi * 8;
    afr[ks] = pack8(*(const float4*)p, *(const float4*)(p + 4));
  }

  // stage chunk 0
#pragma unroll
  for (int i = 0; i < 8; ++i) {
    int r = i * 8 + r5;
    float4 g = *(const float4*)(F + (size_t)r * DD + sg * 4);
    int off = r * 256 + ((((sg >> 1) ^ (r & 7)) << 4) | ((sg & 1) << 3));
    *(bf16x4*)(Fm + off) = pack4(g);
  }
  __syncthreads();

  float mloc[4], zloc[4];
#pragma unroll
  for (int r = 0; r < 4; ++r) { mloc[r] = -3.0e38f; zloc[r] = 0.0f; }

  for (int mc = 0; mc < NT; mc += 64) {
    const bool more = (mc + 64 < NT);
    float4 G[8];
    if (more) {
      const float* Fs = F + (size_t)(mc + 64) * DD;
#pragma unroll
      for (int i = 0; i < 8; ++i)
        G[i] = *(const float4*)(Fs + (size_t)(i * 8 + r5) * DD + sg * 4);
    }

    f32x4 acc[4];
#pragma unroll
    for (int ct = 0; ct < 4; ++ct) acc[ct] = (f32x4){0.f, 0.f, 0.f, 0.f};
#pragma unroll
    for (int ks = 0; ks < 4; ++ks) {
#pragma unroll
      for (int ct = 0; ct < 4; ++ct) {
        bf16x8 bb = *(const bf16x8*)(Fm + (ct * 16 + lrow) * 256 +
                                     ((ks * 64 + hi * 16) ^ swl));
        acc[ct] = MFMA16(afr[ks], bb, acc[ct]);
      }
    }
    // online stats (round-1 math verbatim)
#pragma unroll
    for (int r = 0; r < 4; ++r) {
      float s0 = acc[0][r], s1 = acc[1][r], s2 = acc[2][r], s3 = acc[3][r];
      float cmx = fmaxf(fmaxf(s0, s1), fmaxf(s2, s3));
      if (cmx > mloc[r]) {
        zloc[r] *= __expf(mloc[r] - cmx);
        mloc[r] = cmx;
      }
      zloc[r] += __expf(s0 - mloc[r]) + __expf(s1 - mloc[r]) +
                 __expf(s2 - mloc[r]) + __expf(s3 - mloc[r]);
    }

    __syncthreads();
    if (more) {
#pragma unroll
      for (int i = 0; i < 8; ++i) {
        int r = i * 8 + r5;
        int off = r * 256 + ((((sg >> 1) ^ (r & 7)) << 4) | ((sg & 1) << 3));
        *(bf16x4*)(Fm + off) = pack4(G[i]);
      }
    }
    __syncthreads();
  }

  // reduce across the 16 lanes sharing rows (round-1 verbatim)
#pragma unroll
  for (int r = 0; r < 4; ++r) {
    float m = mloc[r], z = zloc[r];
#pragma unroll
    for (int off = 1; off < 16; off <<= 1) {
      float mo = __shfl_xor(m, off, 64);
      float zo = __shfl_xor(z, off, 64);
      float mn = fmaxf(m, mo);
      z = z * __expf(m - mn) + zo * __expf(mo - mn);
      m = mn;
    }
    mloc[r] = m; zloc[r] = z;
  }
  if ((lane & 15) == 0) {
    int rowbase = nb + wb + hi * 4;
#pragma unroll
    for (int r = 0; r < 4; ++r)
      stats[(size_t)b * NT + rowbase + r] = make_float2(mloc[r], 1.0f / zloc[r]);
  }
}

// ---------------------------------------------------------------------------
// Kernel 2: O[:, mtile128] = F^T W. grid 256: b=blk&7, mb0=(blk>>3)*128.
// Per wave: 32 m-cols; GEMM1 B (m-rows of F) in registers; Fn + Ftt staged
// (swizzled); W via wave-private LDS round-trip (no extra barrier).
// ---------------------------------------------------------------------------
__global__ __launch_bounds__(256, 2) void cab_out(const float* __restrict__ x,
                                                  const ushort* __restrict__ Ftb,
                                                  const float2* __restrict__ stats,
                                                  float* __restrict__ out) {
  const int b = blockIdx.x & 7;
  const int mb0 = (blockIdx.x >> 3) * 128;
  const float* F = x + (size_t)b * NT * DD;
  const ushort* Ft = Ftb + (size_t)b * DD * NT;
  const float2* st = stats + (size_t)b * NT;

  const int t = threadIdx.x, lane = t & 63, wv = t >> 6;
  const int lrow = lane & 15, hi = lane >> 4;
  const int r5 = t >> 5, sg = t & 31;
  const int d8 = t >> 3, sgn = t & 7;  // Ftt staging: 8 lanes per d-row
  const int swl = (lrow & 7) << 4;

  __shared__ __align__(16) char Fn[64 * 256];    // [n 0..63][128 d] bf16, swz
  __shared__ __align__(16) char Ftt[128 * 128];  // [d 0..127][64 n] bf16, swz
  __shared__ __align__(16) char Wt[128 * 128];   // [m 0..127][64 n] bf16, swz
  __shared__ float2 sst[64];

  // GEMM1 B-operand: m-rows of F in registers for whole kernel
  bf16x8 fmf[2][4];
#pragma unroll
  for (int ms = 0; ms < 2; ++ms)
#pragma unroll
    for (int ks = 0; ks < 4; ++ks) {
      const float* p =
          F + (size_t)(mb0 + wv * 32 + ms * 16 + lrow) * DD + ks * 32 + hi * 8;
      fmf[ms][ks] = pack8(*(const float4*)p, *(const float4*)(p + 4));
    }

  // prologue: stage step 0
#pragma unroll
  for (int i = 0; i < 8; ++i) {
    int n = i * 8 + r5;
    float4 g = *(const float4*)(F + (size_t)n * DD + sg * 4);
    int off = n * 256 + ((((sg >> 1) ^ (n & 7)) << 4) | ((sg & 1) << 3));
    *(bf16x4*)(Fn + off) = pack4(g);
  }
#pragma unroll
  for (int i = 0; i < 4; ++i) {
    int d = i * 32 + d8;
    uint4 v = *(const uint4*)(Ft + (size_t)d * NT + sgn * 8);
    *(uint4*)(Ftt + d * 128 + ((sgn ^ (d & 7)) << 4)) = v;
  }
  if (t < 64) sst[t] = st[t];
  __syncthreads();

  f32x4 accO[2][8];
#pragma unroll
  for (int ms = 0; ms < 2; ++ms)
#pragma unroll
    for (int dt = 0; dt < 8; ++dt) accO[ms][dt] = (f32x4){0.f, 0.f, 0.f, 0.f};

  for (int s = 0; s < 64; ++s) {
    const bool more = (s < 63);

    // issue-early next-step global loads
    float4 GF[8];
    uint4 GT[4];
    float2 Gs;
    if (more) {
      const float* Fs = F + (size_t)(s + 1) * 64 * DD;
#pragma unroll
      for (int i = 0; i < 8; ++i)
        GF[i] = *(const float4*)(Fs + (size_t)(i * 8 + r5) * DD + sg * 4);
#pragma unroll
      for (int i = 0; i < 4; ++i) {
        int d = i * 32 + d8;
        GT[i] = *(const uint4*)(Ft + (size_t)d * NT + (s + 1) * 64 + sgn * 8);
      }
      if (t < 64) Gs = st[(s + 1) * 64 + t];
    }

    // GEMM1: S[64 n][32 m-per-wave]  (chain order identical to k1 -> S bit-exact)
    f32x4 sacc[2][4];
#pragma unroll
    for (int ms = 0; ms < 2; ++ms)
#pragma unroll
      for (int nt = 0; nt < 4; ++nt) sacc[ms][nt] = (f32x4){0.f, 0.f, 0.f, 0.f};
#pragma unroll
    for (int nt = 0; nt < 4; ++nt) {
#pragma unroll
      for (int ks = 0; ks < 4; ++ks) {
        bf16x8 a = *(const bf16x8*)(Fn + (nt * 16 + lrow) * 256 +
                                    ((ks * 64 + hi * 16) ^ swl));
#pragma unroll
        for (int ms = 0; ms < 2; ++ms)
          sacc[ms][nt] = MFMA16(a, fmf[ms][ks], sacc[ms][nt]);
      }
    }

    // W = exp(S - m) * invZ -> wave-private Wt rows [wv*32, wv*32+32)
#pragma unroll
    for (int ms = 0; ms < 2; ++ms) {
      const int mrow = wv * 32 + ms * 16 + lrow;
#pragma unroll
      for (int nt = 0; nt < 4; ++nt) {
        ushort4 wp;
#pragma unroll
        for (int r = 0; r < 4; ++r) {
          float2 s2 = sst[nt * 16 + hi * 4 + r];
          float w = __expf(sacc[ms][nt][r] - s2.x) * s2.y;
          ((unsigned short*)&wp)[r] = __builtin_bit_cast(unsigned short, (__bf16)w);
        }
        int blkc = (2 * nt + (hi >> 1)) ^ (lrow & 7);
        *(ushort4*)(Wt + mrow * 128 + (blkc << 4) + ((hi & 1) << 3)) = wp;
      }
    }

    // GEMM2: accO += Ftt(A:[d][n]) x Wt(B:[m][n]); same-wave LDS dep (lgkmcnt)
#pragma unroll
    for (int kk = 0; kk < 2; ++kk) {
      const int cblk = ((4 * kk + hi) ^ (lrow & 7)) << 4;
      bf16x8 b2[2];
#pragma unroll
      for (int ms = 0; ms < 2; ++ms)
        b2[ms] = *(const bf16x8*)(Wt + (wv * 32 + ms * 16 + lrow) * 128 + cblk);
#pragma unroll
      for (int dt = 0; dt < 8; ++dt) {
        bf16x8 a2 = *(const bf16x8*)(Ftt + (dt * 16 + lrow) * 128 + cblk);
#pragma unroll
        for (int ms = 0; ms < 2; ++ms)
          accO[ms][dt] = MFMA16(a2, b2[ms], accO[ms][dt]);
      }
    }

    __syncthreads();
    if (more) {
#pragma unroll
      for (int i = 0; i < 8; ++i) {
        int n = i * 8 + r5;
        int off = n * 256 + ((((sg >> 1) ^ (n & 7)) << 4) | ((sg & 1) << 3));
        *(bf16x4*)(Fn + off) = pack4(GF[i]);
      }
#pragma unroll
      for (int i = 0; i < 4; ++i) {
        int d = i * 32 + d8;
        *(uint4*)(Ftt + d * 128 + ((sgn ^ (d & 7)) << 4)) = GT[i];
      }
      if (t < 64) sst[t] = Gs;
    }
    __syncthreads();
  }

  // epilogue: D row = d = dt*16 + hi*4 + r, col = m
  float* Ob = out + (size_t)b * DD * NT;
  const int m = mb0 + wv * 32 + lrow;
#pragma unroll
  for (int ms = 0; ms < 2; ++ms)
#pragma unroll
    for (int dt = 0; dt < 8; ++dt)
#pragma unroll
      for (int r = 0; r < 4; ++r)
        Ob[(size_t)(dt * 16 + hi * 4 + r) * NT + m + ms * 16] = accO[ms][dt][r];
}

extern "C" void kernel_launch(void* const* d_in, const int* in_sizes, int n_in,
                              void* d_out, int out_size, void* d_ws, size_t ws_size,
                              hipStream_t stream) {
  const float* x = (const float*)d_in[0];
  float* out = (float*)d_out;
  float2* stats = (float2*)d_ws;                          // 256 KB
  ushort* Ftb = (ushort*)((char*)d_ws + 262144);          // 8 MB

  hipLaunchKernelGGL(cab_transpose, dim3(4096), dim3(256), 0, stream, x, Ftb);
  hipLaunchKernelGGL(cab_rowstats, dim3(512), dim3(256), 0, stream, x, stats);
  hipLaunchKernelGGL(cab_out, dim3(256), dim3(256), 0, stream, x, Ftb, stats, out);
}

// Round 4
// 176.807 us; speedup vs baseline: 2.7343x; 1.7207x over previous
//
#include <hip/hip_runtime.h>

// ChannelAttentionBlock: per batch b, F = x[b] viewed as [4096,128] (row-major).
// S = F F^T ; P = softmax rows ; out[b] = F^T P -> [128, 4096].
//
// k0a cab_cast     : Fbb[b][n][d] = bf16(x)            (8 MB ws)
// k0b cab_transpose: Ftb[b][d][n] = bf16(x)            (8 MB ws)
// k1  cab_rowstats : c2[n] = -(max_m(S*log2e) + log2 Z) (128 KB ws)
// k2  cab_out      : recompute S, W = 2^(S*log2e + c2), O += F^T W
//
// S is bit-identical between k1/k2: identical bf16 operand bytes (from Fbb)
// through identical ks-ordered MFMA chains. All LDS tiles: linear rows,
// 16B-chunk XOR swizzle  chunk' = chunk ^ (row & 7)  on write(src) and read.
// Staging via __builtin_amdgcn_global_load_lds (linear dest, pre-swizzled
// per-lane global source).

typedef __attribute__((ext_vector_type(8))) __bf16 bf16x8;
typedef __attribute__((ext_vector_type(4))) float f32x4;

#define MFMA16(a, b, c) __builtin_amdgcn_mfma_f32_16x16x32_bf16((a), (b), (c), 0, 0, 0)
#define GLOAD16(g, l)                                                       \
  __builtin_amdgcn_global_load_lds(                                         \
      (const __attribute__((address_space(1))) void*)(g),                   \
      (__attribute__((address_space(3))) void*)(l), 16, 0, 0)
#define GLOAD4(g, l)                                                        \
  __builtin_amdgcn_global_load_lds(                                         \
      (const __attribute__((address_space(1))) void*)(g),                   \
      (__attribute__((address_space(3))) void*)(l), 4, 0, 0)

static constexpr int NT = 4096;
static constexpr int DD = 128;
static constexpr float L2E = 1.4426950408889634f;

__device__ __forceinline__ unsigned short bfc(float f) {
  return __builtin_bit_cast(unsigned short, (__bf16)f);
}

// ---------------------------------------------------------------------------
// k0a: row-major cast x -> Fbb bf16. grid 2048.
// ---------------------------------------------------------------------------
__global__ __launch_bounds__(256) void cab_cast(const float* __restrict__ x,
                                                ushort* __restrict__ Fbb) {
  size_t i = ((size_t)blockIdx.x * 256 + threadIdx.x) * 8;
  float4 a = *(const float4*)(x + i);
  float4 b = *(const float4*)(x + i + 4);
  ushort4 lo = make_ushort4(bfc(a.x), bfc(a.y), bfc(a.z), bfc(a.w));
  ushort4 hi = make_ushort4(bfc(b.x), bfc(b.y), bfc(b.z), bfc(b.w));
  *(ushort4*)(Fbb + i) = lo;
  *(ushort4*)(Fbb + i + 4) = hi;
}

// ---------------------------------------------------------------------------
// k0b: transpose+cast x -> Ftb[b][d][n]. grid 4096. (round-3 verbatim)
// ---------------------------------------------------------------------------
__global__ __launch_bounds__(256) void cab_transpose(const float* __restrict__ x,
                                                     ushort* __restrict__ Ftb) {
  const int blk = blockIdx.x;
  const int b = blk & 7, seg = blk >> 3;
  const int d = seg >> 2, n0 = (seg & 3) * 1024;
  const float* F = x + (size_t)b * NT * DD;
  ushort* Ob = Ftb + (size_t)b * DD * NT;
  const int n = n0 + threadIdx.x * 4;
  ushort4 w;
  w.x = bfc(F[(size_t)(n + 0) * DD + d]);
  w.y = bfc(F[(size_t)(n + 1) * DD + d]);
  w.z = bfc(F[(size_t)(n + 2) * DD + d]);
  w.w = bfc(F[(size_t)(n + 3) * DD + d]);
  *(ushort4*)(Ob + (size_t)d * NT + n) = w;
}

// ---------------------------------------------------------------------------
// k1: row stats. grid 512: b=blk&7, nb=(blk>>3)*64. 1 barrier/step.
// ---------------------------------------------------------------------------
__global__ __launch_bounds__(256, 2) void cab_rowstats(const ushort* __restrict__ Fbb,
                                                       float* __restrict__ c2g) {
  const int b = blockIdx.x & 7, nb = (blockIdx.x >> 3) * 64;
  const ushort* Fb = Fbb + (size_t)b * NT * DD;

  const int t = threadIdx.x, lane = t & 63, wv = t >> 6;
  const int lrow = lane & 15, hi = lane >> 4, wb = wv * 16, swl = lrow & 7;

  __shared__ __align__(16) char FmB[2][16384];  // [64 m][128 d] bf16, swz

  // gload per-lane source element offsets (dest rows (wv*4+i)*4 + lane>>4)
  int fmsrc[4];
#pragma unroll
  for (int i = 0; i < 4; ++i) {
    int r = wv * 16 + i * 4 + (lane >> 4), c = lane & 15;
    fmsrc[i] = r * DD + ((c ^ (r & 7)) * 8);
  }

  // A fragments (own n-rows) from global, bf16x8
  bf16x8 afr[4];
#pragma unroll
  for (int ks = 0; ks < 4; ++ks)
    afr[ks] = *(const bf16x8*)(Fb + (size_t)(nb + wb + lrow) * DD + ks * 32 + hi * 8);

  // prologue: stage m-chunk 0
#pragma unroll
  for (int i = 0; i < 4; ++i)
    GLOAD16(Fb + fmsrc[i], &FmB[0][(wv * 4 + i) * 1024]);
  __syncthreads();

  float mloc[4], zloc[4];
#pragma unroll
  for (int r = 0; r < 4; ++r) { mloc[r] = -1.0e30f; zloc[r] = 0.0f; }

  for (int mc = 0; mc < NT; mc += 64) {
    const int cur = (mc >> 6) & 1;
    if (mc + 64 < NT) {
      const ushort* src = Fb + (size_t)(mc + 64) * DD;
#pragma unroll
      for (int i = 0; i < 4; ++i)
        GLOAD16(src + fmsrc[i], &FmB[cur ^ 1][(wv * 4 + i) * 1024]);
    }

    f32x4 acc[4];
#pragma unroll
    for (int ct = 0; ct < 4; ++ct) acc[ct] = (f32x4){0.f, 0.f, 0.f, 0.f};
#pragma unroll
    for (int ks = 0; ks < 4; ++ks) {
#pragma unroll
      for (int ct = 0; ct < 4; ++ct) {
        bf16x8 bb = *(const bf16x8*)&FmB[cur][(ct * 16 + lrow) * 256 +
                                             (((ks * 4 + hi) ^ swl) << 4)];
        acc[ct] = MFMA16(afr[ks], bb, acc[ct]);
      }
    }
    // online stats in log2 domain
#pragma unroll
    for (int r = 0; r < 4; ++r) {
      float s0 = acc[0][r] * L2E, s1 = acc[1][r] * L2E;
      float s2 = acc[2][r] * L2E, s3 = acc[3][r] * L2E;
      float cmx = fmaxf(fmaxf(s0, s1), fmaxf(s2, s3));
      float mn = fmaxf(mloc[r], cmx);
      zloc[r] = zloc[r] * __builtin_amdgcn_exp2f(mloc[r] - mn) +
                __builtin_amdgcn_exp2f(s0 - mn) + __builtin_amdgcn_exp2f(s1 - mn) +
                __builtin_amdgcn_exp2f(s2 - mn) + __builtin_amdgcn_exp2f(s3 - mn);
      mloc[r] = mn;
    }
    __syncthreads();  // drains gloads (vmcnt 0) + publishes buf cur^1
  }

  // reduce across the 16 lanes sharing rows
#pragma unroll
  for (int r = 0; r < 4; ++r) {
    float m = mloc[r], z = zloc[r];
#pragma unroll
    for (int off = 1; off < 16; off <<= 1) {
      float mo = __shfl_xor(m, off, 64);
      float zo = __shfl_xor(z, off, 64);
      float mn = fmaxf(m, mo);
      z = z * __builtin_amdgcn_exp2f(m - mn) + zo * __builtin_amdgcn_exp2f(mo - mn);
      m = mn;
    }
    if (lrow == 0) c2g[(size_t)b * NT + nb + wb + hi * 4 + r] = -(m + __log2f(z));
  }
}

// ---------------------------------------------------------------------------
// k2: O[:, mtile64] = F^T W. grid 512: b=blk&7, mb0=(blk>>3)*64.
// GEMM1: wave owns 16 m (fmf in regs). GEMM2: wave owns 32 d-rows.
// ---------------------------------------------------------------------------
__global__ __launch_bounds__(256, 2) void cab_out(const ushort* __restrict__ Fbb,
                                                  const ushort* __restrict__ Ftb,
                                                  const float* __restrict__ c2g,
                                                  float* __restrict__ out) {
  const int b = blockIdx.x & 7, mb0 = (blockIdx.x >> 3) * 64;
  const ushort* Fb = Fbb + (size_t)b * NT * DD;
  const ushort* Ft = Ftb + (size_t)b * DD * NT;
  const float* c2p = c2g + (size_t)b * NT;

  const int t = threadIdx.x, lane = t & 63, wv = t >> 6;
  const int lrow = lane & 15, hi = lane >> 4, swl = lrow & 7;

  __shared__ __align__(16) char FnB[2][16384];   // [64 n][128 d] bf16, swz
  __shared__ __align__(16) char FttB[2][16384];  // [128 d][64 n] bf16, swz
  __shared__ __align__(16) char WtB[8192];       // [64 m][64 n] bf16, swz
  __shared__ __align__(16) float c2l[2][64];

  // gload per-lane source element offsets
  int fnsrc[4], fttsrc[4];
#pragma unroll
  for (int i = 0; i < 4; ++i) {
    int r = wv * 16 + i * 4 + (lane >> 4), c = lane & 15;
    fnsrc[i] = r * DD + ((c ^ (r & 7)) * 8);
    int d = wv * 32 + i * 8 + (lane >> 3), cc = lane & 7;
    fttsrc[i] = d * NT + ((cc ^ (d & 7)) * 8);
  }

  // GEMM1 B-operand: wave's 16 m-rows, in registers for whole kernel
  bf16x8 fmf[4];
#pragma unroll
  for (int ks = 0; ks < 4; ++ks)
    fmf[ks] = *(const bf16x8*)(Fb + (size_t)(mb0 + wv * 16 + lrow) * DD + ks * 32 + hi * 8);

  f32x4 accO[2][4];
#pragma unroll
  for (int dt = 0; dt < 2; ++dt)
#pragma unroll
    for (int ms = 0; ms < 4; ++ms) accO[dt][ms] = (f32x4){0.f, 0.f, 0.f, 0.f};

  // prologue: stage step 0
#pragma unroll
  for (int i = 0; i < 4; ++i)
    GLOAD16(Fb + fnsrc[i], &FnB[0][(wv * 4 + i) * 1024]);
#pragma unroll
  for (int i = 0; i < 4; ++i)
    GLOAD16(Ft + fttsrc[i], &FttB[0][(wv * 4 + i) * 1024]);
  if (wv == 0) GLOAD4(c2p + lane, &c2l[0][0]);
  __syncthreads();

  for (int s = 0; s < 64; ++s) {
    const int cur = s & 1;
    if (s < 63) {
      const ushort* fs = Fb + (size_t)(s + 1) * 8192;
      const ushort* ts = Ft + (s + 1) * 64;
#pragma unroll
      for (int i = 0; i < 4; ++i)
        GLOAD16(fs + fnsrc[i], &FnB[cur ^ 1][(wv * 4 + i) * 1024]);
#pragma unroll
      for (int i = 0; i < 4; ++i)
        GLOAD16(ts + fttsrc[i], &FttB[cur ^ 1][(wv * 4 + i) * 1024]);
      if (wv == 0) GLOAD4(c2p + (s + 1) * 64 + lane, &c2l[cur ^ 1][0]);
    }

    // GEMM1: S[64 n][16 m]; chain identical to k1 -> S bit-exact
    f32x4 sacc[4];
#pragma unroll
    for (int nt = 0; nt < 4; ++nt) sacc[nt] = (f32x4){0.f, 0.f, 0.f, 0.f};
#pragma unroll
    for (int nt = 0; nt < 4; ++nt)
#pragma unroll
      for (int ks = 0; ks < 4; ++ks) {
        bf16x8 a = *(const bf16x8*)&FnB[cur][(nt * 16 + lrow) * 256 +
                                            (((ks * 4 + hi) ^ swl) << 4)];
        sacc[nt] = MFMA16(a, fmf[ks], sacc[nt]);
      }

    // GEMM2 A-frags (independent of W) — read before barrier #1
    bf16x8 a2[2][2];
#pragma unroll
    for (int dt = 0; dt < 2; ++dt)
#pragma unroll
      for (int kk = 0; kk < 2; ++kk)
        a2[dt][kk] = *(const bf16x8*)&FttB[cur][(wv * 32 + dt * 16 + lrow) * 128 +
                                               (((kk * 4 + hi) ^ swl) << 4)];

    // W = 2^(S*log2e + c2) -> WtB rows [wv*16, wv*16+16)
    const int mrow = wv * 16 + lrow;
#pragma unroll
    for (int nt = 0; nt < 4; ++nt) {
      float4 cv = *(const float4*)&c2l[cur][nt * 16 + hi * 4];
      ushort4 wp;
      wp.x = bfc(__builtin_amdgcn_exp2f(fmaf(sacc[nt][0], L2E, cv.x)));
      wp.y = bfc(__builtin_amdgcn_exp2f(fmaf(sacc[nt][1], L2E, cv.y)));
      wp.z = bfc(__builtin_amdgcn_exp2f(fmaf(sacc[nt][2], L2E, cv.z)));
      wp.w = bfc(__builtin_amdgcn_exp2f(fmaf(sacc[nt][3], L2E, cv.w)));
      *(ushort4*)&WtB[mrow * 128 + (((nt * 2 + (hi >> 1)) ^ swl) << 4) + (hi & 1) * 8] = wp;
    }

    __syncthreads();  // #1: W published (also drains this step's gloads)

    // GEMM2: accO[dt][ms] += Ftt(A:[d][n]) x Wt(B:[m][n]), K=64 over kk
#pragma unroll
    for (int kk = 0; kk < 2; ++kk)
#pragma unroll
      for (int ms = 0; ms < 4; ++ms) {
        bf16x8 b2 = *(const bf16x8*)&WtB[(ms * 16 + lrow) * 128 +
                                         (((kk * 4 + hi) ^ swl) << 4)];
#pragma unroll
        for (int dt = 0; dt < 2; ++dt)
          accO[dt][ms] = MFMA16(a2[dt][kk], b2, accO[dt][ms]);
      }

    __syncthreads();  // #2: all Wt reads done; buffers flip
  }

  // epilogue: D row = d = wv*32 + dt*16 + hi*4 + r, col = m = mb0 + ms*16 + lrow
  float* Ob = out + (size_t)b * DD * NT;
#pragma unroll
  for (int dt = 0; dt < 2; ++dt)
#pragma unroll
    for (int ms = 0; ms < 4; ++ms)
#pragma unroll
      for (int r = 0; r < 4; ++r) {
        int d = wv * 32 + dt * 16 + hi * 4 + r;
        int m = mb0 + ms * 16 + lrow;
        Ob[(size_t)d * NT + m] = accO[dt][ms][r];
      }
}

extern "C" void kernel_launch(void* const* d_in, const int* in_sizes, int n_in,
                              void* d_out, int out_size, void* d_ws, size_t ws_size,
                              hipStream_t stream) {
  const float* x = (const float*)d_in[0];
  float* out = (float*)d_out;
  ushort* Fbb = (ushort*)d_ws;                              // 8 MB
  ushort* Ftb = (ushort*)((char*)d_ws + (8u << 20));        // 8 MB
  float* c2 = (float*)((char*)d_ws + (16u << 20));          // 128 KB

  hipLaunchKernelGGL(cab_cast, dim3(2048), dim3(256), 0, stream, x, Fbb);
  hipLaunchKernelGGL(cab_transpose, dim3(4096), dim3(256), 0, stream, x, Ftb);
  hipLaunchKernelGGL(cab_rowstats, dim3(512), dim3(256), 0, stream, Fbb, c2);
  hipLaunchKernelGGL(cab_out, dim3(512), dim3(256), 0, stream, Fbb, Ftb, c2, out);
}